// Round 7
// baseline (322.737 us; speedup 1.0000x reference)
//
#include <hip/hip_runtime.h>
#include <math.h>

// PhysQuadModel: batched RK4 rollout of quadrotor dynamics.
// R2: quaternion carried as loop state (exp(log(q))==q), poly atan2 for the
//     output-only log map, reciprocal-multiplies, v_rsq normalize.
// R3/R6: deep software prefetch of u (227->194us rocprof).
// R5 lesson: NT stores = 3.6x write amplification on this layout. Normal stores.
// R7: VALUBusy hit 10.5% vs the 12.5% ceiling of 128 waves/1024 SIMDs ->
//     issue-bound. gfx950 packed fp32 (v_pk_fma_f32, full rate — it's how the
//     157 TF spec is reached) -> TWO trajectories per thread, every state var
//     a float2 ext-vector. Same instruction stream now advances 2 trajectories.
//     64 waves, ~half the issue cycles per trajectory-step.

namespace {
constexpr int   kB    = 8192;
constexpr int   kN    = 256;
constexpr float kDT   = 0.01f;
constexpr float kMG   = 0.033f * 9.81f;        // M*G
constexpr float kTmax = 1.9f * 0.033f * 9.81f; // 0.6150870
constexpr float kKT   = 3.8e-08f;
constexpr float kKC   = 3.8e-11f;
constexpr float kArm  = 0.04f;
constexpr float kInvM = 1.0f / 0.033f;
constexpr float kJx   = 1.4e-05f, kJy = 1.4e-05f, kJz = 2.17e-05f;
constexpr float kInvJx = 1.0f / 1.4e-05f, kInvJy = 1.0f / 1.4e-05f,
                kInvJz = 1.0f / 2.17e-05f;
constexpr float kTq0  = 0.009f, kTq1 = 0.009f, kTq2 = 0.002f;
constexpr float kH    = 0.005f;                // 0.5*dt
constexpr float kDT6  = 0.0016666667f;         // dt/6
constexpr int   kPF   = 4;                     // prefetch depth (pair-bodies)
}

typedef float f2 __attribute__((ext_vector_type(2)));

__device__ __forceinline__ float fast_rcp(float x) { return __builtin_amdgcn_rcpf(x); }
__device__ __forceinline__ float fast_rsq(float x) { return __builtin_amdgcn_rsqf(x); }

__device__ __forceinline__ f2 s2(float v) { f2 r; r.x = v; r.y = v; return r; }
__device__ __forceinline__ f2 rcp2(f2 v) { f2 r; r.x = fast_rcp(v.x); r.y = fast_rcp(v.y); return r; }
__device__ __forceinline__ f2 min2(f2 a, f2 b) { return __builtin_elementwise_min(a, b); }
__device__ __forceinline__ f2 max2(f2 a, f2 b) { return __builtin_elementwise_max(a, b); }
__device__ __forceinline__ f2 abs2(f2 a) { return __builtin_elementwise_abs(a); }

// packed atan2 for y >= 0, result in [0, pi]. Minimax poly, err ~1e-5.
__device__ __forceinline__ f2 atan2_pos2(f2 y, f2 x) {
  f2 axx = abs2(x);
  f2 mn  = min2(y, axx);
  f2 mx  = max2(y, axx);
  f2 t   = mn * rcp2(mx);
  f2 t2  = t * t;
  f2 p = t2 * s2(-0.01172120f) + s2(0.05265332f);
  p = t2 * p + s2(-0.11643287f);
  p = t2 * p + s2(0.19354346f);
  p = t2 * p + s2(-0.33262347f);
  p = t2 * p + s2(0.99997726f);
  p *= t;
  p.x = (y.x > axx.x) ? (1.5707963268f - p.x) : p.x;
  p.y = (y.y > axx.y) ? (1.5707963268f - p.y) : p.y;
  p.x = (x.x < 0.0f) ? (3.1415926536f - p.x) : p.x;
  p.y = (x.y < 0.0f) ? (3.1415926536f - p.y) : p.y;
  return p;
}

// accurate scalar version used ONCE at init (outside the hot loop)
__device__ __forceinline__ void so3_to_quat_init(float rx, float ry, float rz,
                                                 float& qx, float& qy, float& qz, float& qw) {
  float theta = sqrtf(rx * rx + ry * ry + rz * rz);
  float half  = 0.5f * theta;
  float s     = sinf(half);
  float c     = cosf(half);
  float k     = s / (theta + 1e-8f);
  bool  small = theta < 1e-6f;
  k  = small ? 0.5f : k;
  qw = small ? 1.0f : c;
  qx = k * rx; qy = k * ry; qz = k * rz;
}

// packed log map, output-only path (not fed back into state)
__device__ __forceinline__ void quat_to_so3_fast2(f2 qx, f2 qy, f2 qz, f2 qw,
                                                  f2& rx, f2& ry, f2& rz) {
  f2 nv2 = qx * qx + qy * qy + qz * qz;
  f2 nv;
  nv.x = nv2.x * fast_rsq(fmaxf(nv2.x, 1e-20f));
  nv.y = nv2.y * fast_rsq(fmaxf(nv2.y, 1e-20f));
  f2 wc  = min2(max2(qw, s2(-0.999999f)), s2(0.999999f));
  f2 ang = s2(2.0f) * atan2_pos2(nv, wc);
  f2 k   = ang * rcp2(nv + s2(1e-6f));
  k.x = (nv.x < 1e-6f) ? 2.0f : k.x;
  k.y = (nv.y < 1e-6f) ? 2.0f : k.y;
  rx = k * qx; ry = k * qy; rz = k * qz;
}

__device__ __forceinline__ void normalize4_fast2(f2& x, f2& y, f2& z, f2& w) {
  f2 n2 = x * x + y * y + z * z + w * w;
  f2 inv;
  inv.x = fast_rsq(n2.x);
  inv.y = fast_rsq(n2.y);
  x *= inv; y *= inv; z *= inv; w *= inv;
}

// packed dyn core: everything element-wise over the trajectory pair.
__device__ __forceinline__ void dyn_core2(
    f2 qx, f2 qy, f2 qz, f2 qw,
    f2 wx, f2 wy, f2 wz,
    f2 T, f2 tqx, f2 tqy, f2 tqz,
    f2& ax, f2& ay, f2& az,
    f2& qdx, f2& qdy, f2& qdz, f2& qdw,
    f2& wdx, f2& wdy, f2& wdz) {
  // thrust_w = quat_rotate(q, (0,0,T)); t = 2*cross(qv,(0,0,T)) = (2qyT, -2qxT, 0)
  f2 tx = s2(2.0f) * (qy * T);
  f2 ty = s2(-2.0f) * (qx * T);
  f2 cx = -qz * ty;
  f2 cy =  qz * tx;
  f2 cz = qx * ty - qy * tx;
  ax = (qw * tx + cx) * s2(kInvM);
  ay = (qw * ty + cy) * s2(kInvM);
  az = (T + cz - s2(kMG)) * s2(kInvM);

  // omega_dot = J^-1 (tau - omega x (J omega)); J diagonal
  f2 Jwx = s2(kJx) * wx, Jwy = s2(kJy) * wy, Jwz = s2(kJz) * wz;
  wdx = (tqx - (wy * Jwz - wz * Jwy)) * s2(kInvJx);
  wdy = (tqy - (wz * Jwx - wx * Jwz)) * s2(kInvJy);
  wdz = (tqz - (wx * Jwy - wy * Jwx)) * s2(kInvJz);

  // quat derivative
  qdx = s2(0.5f) * (qw * wx + (qy * wz - qz * wy));
  qdy = s2(0.5f) * (qw * wy + (qz * wx - qx * wz));
  qdz = s2(0.5f) * (qw * wz + (qx * wy - qy * wx));
  qdw = s2(-0.5f) * (qx * wx + qy * wy + qz * wz);
}

__global__ __launch_bounds__(64) void quad_rk4_kernel(
    const float* __restrict__ x0,
    const float* __restrict__ u_seq,
    float* __restrict__ out) {
  const int tid = blockIdx.x * 64 + threadIdx.x;   // 4096 threads
  const int bA = 2 * tid, bB = 2 * tid + 1;

  // load both trajectories' initial states
  const float4* xvA = reinterpret_cast<const float4*>(x0) + (size_t)bA * 3;
  const float4* xvB = reinterpret_cast<const float4*>(x0) + (size_t)bB * 3;
  float4 a0 = xvA[0], a1 = xvA[1], a2 = xvA[2];
  float4 b0 = xvB[0], b1 = xvB[1], b2 = xvB[2];

  f2 px = {a0.x, b0.x}, py = {a0.y, b0.y}, pz = {a0.z, b0.z};
  f2 vx = {a0.w, b0.w}, vy = {a1.x, b1.x}, vz = {a1.y, b1.y};
  f2 ox = {a2.y, b2.y}, oy = {a2.z, b2.z}, oz = {a2.w, b2.w};

  float qxa, qya, qza, qwa, qxb, qyb, qzb, qwb;
  so3_to_quat_init(a1.z, a1.w, a2.x, qxa, qya, qza, qwa);
  so3_to_quat_init(b1.z, b1.w, b2.x, qxb, qyb, qzb, qwb);
  f2 qx = {qxa, qxb}, qy = {qya, qyb}, qz = {qza, qzb}, qw = {qwa, qwb};

  const float4* uvA = reinterpret_cast<const float4*>(u_seq) + (size_t)bA * kN;
  const float4* uvB = reinterpret_cast<const float4*>(u_seq) + (size_t)bB * kN;
  float4* ovA = reinterpret_cast<float4*>(out) + (size_t)bA * kN * 3;
  float4* ovB = reinterpret_cast<float4*>(out) + (size_t)bB * kN * 3;

  // depth-4 prefetch pipeline per trajectory (8 loads in flight total)
  float4 uA0 = uvA[0], uA1 = uvA[1], uA2 = uvA[2], uA3 = uvA[3];
  float4 uB0 = uvB[0], uB1 = uvB[1], uB2 = uvB[2], uB3 = uvB[3];

#pragma unroll 4
  for (int t = 0; t < kN; ++t) {
    int tp = (t + kPF < kN) ? (t + kPF) : (kN - 1);
    float4 uAn = uvA[tp];
    float4 uBn = uvB[tp];

    // motor_to_phys (scalar per traj, then packed): T=min(KT*s,Tmax), tau=clamp
    f2 T, tq1, tq2, tq3;
    {
      float w20 = uA0.x * uA0.x, w21 = uA0.y * uA0.y,
            w22 = uA0.z * uA0.z, w23 = uA0.w * uA0.w;
      T.x   = fminf(kKT * (w20 + w21 + w22 + w23), kTmax);
      tq1.x = kKT * kArm * ((w22 + w23) - (w20 + w21));
      tq2.x = kKT * kArm * ((w21 + w22) - (w20 + w23));
      tq3.x = kKC * ((w20 + w22) - (w21 + w23));
    }
    {
      float w20 = uB0.x * uB0.x, w21 = uB0.y * uB0.y,
            w22 = uB0.z * uB0.z, w23 = uB0.w * uB0.w;
      T.y   = fminf(kKT * (w20 + w21 + w22 + w23), kTmax);
      tq1.y = kKT * kArm * ((w22 + w23) - (w20 + w21));
      tq2.y = kKT * kArm * ((w21 + w22) - (w20 + w23));
      tq3.y = kKC * ((w20 + w22) - (w21 + w23));
    }
    tq1 = min2(max2(tq1, s2(-kTq0)), s2(kTq0));
    tq2 = min2(max2(tq2, s2(-kTq1)), s2(kTq1));
    tq3 = min2(max2(tq3, s2(-kTq2)), s2(kTq2));

    // ---- stage 1 ----
    f2 a1x, a1y, a1z, qd1x, qd1y, qd1z, qd1w, wd1x, wd1y, wd1z;
    dyn_core2(qx, qy, qz, qw, ox, oy, oz, T, tq1, tq2, tq3,
              a1x, a1y, a1z, qd1x, qd1y, qd1z, qd1w, wd1x, wd1y, wd1z);

    // ---- stage 2 ----
    f2 v2x = vx + s2(kH) * a1x, v2y = vy + s2(kH) * a1y, v2z = vz + s2(kH) * a1z;
    f2 o2x = ox + s2(kH) * wd1x, o2y = oy + s2(kH) * wd1y, o2z = oz + s2(kH) * wd1z;
    f2 q2x = qx + s2(kH) * qd1x, q2y = qy + s2(kH) * qd1y,
       q2z = qz + s2(kH) * qd1z, q2w = qw + s2(kH) * qd1w;
    normalize4_fast2(q2x, q2y, q2z, q2w);
    f2 a2x, a2y, a2z, qd2x, qd2y, qd2z, qd2w, wd2x, wd2y, wd2z;
    dyn_core2(q2x, q2y, q2z, q2w, o2x, o2y, o2z, T, tq1, tq2, tq3,
              a2x, a2y, a2z, qd2x, qd2y, qd2z, qd2w, wd2x, wd2y, wd2z);

    // ---- stage 3 ----
    f2 v3x = vx + s2(kH) * a2x, v3y = vy + s2(kH) * a2y, v3z = vz + s2(kH) * a2z;
    f2 o3x = ox + s2(kH) * wd2x, o3y = oy + s2(kH) * wd2y, o3z = oz + s2(kH) * wd2z;
    f2 q3x = qx + s2(kH) * qd2x, q3y = qy + s2(kH) * qd2y,
       q3z = qz + s2(kH) * qd2z, q3w = qw + s2(kH) * qd2w;
    normalize4_fast2(q3x, q3y, q3z, q3w);
    f2 a3x, a3y, a3z, qd3x, qd3y, qd3z, qd3w, wd3x, wd3y, wd3z;
    dyn_core2(q3x, q3y, q3z, q3w, o3x, o3y, o3z, T, tq1, tq2, tq3,
              a3x, a3y, a3z, qd3x, qd3y, qd3z, qd3w, wd3x, wd3y, wd3z);

    // ---- stage 4 (full step) ----
    f2 v4x = vx + s2(kDT) * a3x, v4y = vy + s2(kDT) * a3y, v4z = vz + s2(kDT) * a3z;
    f2 o4x = ox + s2(kDT) * wd3x, o4y = oy + s2(kDT) * wd3y, o4z = oz + s2(kDT) * wd3z;
    f2 q4x = qx + s2(kDT) * qd3x, q4y = qy + s2(kDT) * qd3y,
       q4z = qz + s2(kDT) * qd3z, q4w = qw + s2(kDT) * qd3w;
    normalize4_fast2(q4x, q4y, q4z, q4w);
    f2 a4x, a4y, a4z, qd4x, qd4y, qd4z, qd4w, wd4x, wd4y, wd4z;
    dyn_core2(q4x, q4y, q4z, q4w, o4x, o4y, o4z, T, tq1, tq2, tq3,
              a4x, a4y, a4z, qd4x, qd4y, qd4z, qd4w, wd4x, wd4y, wd4z);

    // ---- RK4 combine (pos uses v1 = old vel; update pos BEFORE vel) ----
    px += s2(kDT6) * (vx + s2(2.0f) * v2x + s2(2.0f) * v3x + v4x);
    py += s2(kDT6) * (vy + s2(2.0f) * v2y + s2(2.0f) * v3y + v4y);
    pz += s2(kDT6) * (vz + s2(2.0f) * v2z + s2(2.0f) * v3z + v4z);
    vx += s2(kDT6) * (a1x + s2(2.0f) * a2x + s2(2.0f) * a3x + a4x);
    vy += s2(kDT6) * (a1y + s2(2.0f) * a2y + s2(2.0f) * a3y + a4y);
    vz += s2(kDT6) * (a1z + s2(2.0f) * a2z + s2(2.0f) * a3z + a4z);
    ox += s2(kDT6) * (wd1x + s2(2.0f) * wd2x + s2(2.0f) * wd3x + wd4x);
    oy += s2(kDT6) * (wd1y + s2(2.0f) * wd2y + s2(2.0f) * wd3y + wd4y);
    oz += s2(kDT6) * (wd1z + s2(2.0f) * wd2z + s2(2.0f) * wd3z + wd4z);
    qx += s2(kDT6) * (qd1x + s2(2.0f) * qd2x + s2(2.0f) * qd3x + qd4x);
    qy += s2(kDT6) * (qd1y + s2(2.0f) * qd2y + s2(2.0f) * qd3y + qd4y);
    qz += s2(kDT6) * (qd1z + s2(2.0f) * qd2z + s2(2.0f) * qd3z + qd4z);
    qw += s2(kDT6) * (qd1w + s2(2.0f) * qd2w + s2(2.0f) * qd3w + qd4w);
    normalize4_fast2(qx, qy, qz, qw);

    // output so3 (not fed back — poly atan2 error does not compound)
    f2 rx, ry, rz;
    quat_to_so3_fast2(qx, qy, qz, qw, rx, ry, rz);

    // normal stores: L2 merges each thread's 2x48 B/step into full lines
    ovA[t * 3 + 0] = make_float4(px.x, py.x, pz.x, vx.x);
    ovA[t * 3 + 1] = make_float4(vy.x, vz.x, rx.x, ry.x);
    ovA[t * 3 + 2] = make_float4(rz.x, ox.x, oy.x, oz.x);
    ovB[t * 3 + 0] = make_float4(px.y, py.y, pz.y, vx.y);
    ovB[t * 3 + 1] = make_float4(vy.y, vz.y, rx.y, ry.y);
    ovB[t * 3 + 2] = make_float4(rz.y, ox.y, oy.y, oz.y);

    // rotate prefetch pipelines
    uA0 = uA1; uA1 = uA2; uA2 = uA3; uA3 = uAn;
    uB0 = uB1; uB1 = uB2; uB2 = uB3; uB3 = uBn;
  }
}

extern "C" void kernel_launch(void* const* d_in, const int* in_sizes, int n_in,
                              void* d_out, int out_size, void* d_ws, size_t ws_size,
                              hipStream_t stream) {
  const float* x0    = (const float*)d_in[0];   // (8192, 12)
  const float* u_seq = (const float*)d_in[1];   // (8192, 256, 4)
  float*       out   = (float*)d_out;           // (8192, 256, 12)
  (void)in_sizes; (void)n_in; (void)out_size; (void)d_ws; (void)ws_size;

  dim3 block(64);
  dim3 grid(kB / 2 / 64);   // 64 blocks = 64 waves, 2 trajectories per thread
  quad_rk4_kernel<<<grid, block, 0, stream>>>(x0, u_seq, out);
}